// Round 4
// baseline (902.905 us; speedup 1.0000x reference)
//
#include <hip/hip_runtime.h>
#include <hip/hip_bf16.h>
#include <math.h>

// Problem constants: B=64, C=20, K=5, Q=15, D=2048
#define BATCH 64
#define NCLS  20
#define NS    100   // C*K
#define NQ    300   // C*Q
#define DIM   2048
#define MS    (BATCH * NS)   // 6400
#define MQ    (BATCH * NQ)   // 19200
#define KSPL  4              // k-split factor for sim GEMM
#define PROW  320            // padded rows per batch in partial buffer
#define PCOL  112            // padded cols per batch in partial buffer

typedef __attribute__((ext_vector_type(8))) short frag_ab;   // 8 bf16 (4 VGPRs)
typedef __attribute__((ext_vector_type(4))) float frag_cd;   // 4 fp32 acc

union FAB { frag_ab f; unsigned u[4]; };

// round-to-nearest-even bf16 hi part, returned as fp32 bit pattern
__device__ __forceinline__ unsigned rne_hi(float x) {
  unsigned u = __float_as_uint(x);
  return (u + 0x7FFFu + ((u >> 16) & 1u)) & 0xFFFF0000u;
}

// 2-level RNE split of pair (x,y): x ~= x1 + x2, |residual| <= 2^-18|x|.
__device__ __forceinline__ void split2rn(float x, float y, unsigned& p1,
                                         unsigned& p2) {
  union { __hip_bfloat162 h; unsigned u; } c1, c2;
  c1.h = __float22bfloat162_rn(make_float2(x, y));
  p1 = c1.u;
  float rx = x - __uint_as_float(c1.u << 16);
  float ry = y - __uint_as_float(c1.u & 0xFFFF0000u);
  c2.h = __float22bfloat162_rn(make_float2(rx, ry));
  p2 = c2.u;
}

#define GLL16(g, l)                                                            \
  __builtin_amdgcn_global_load_lds(                                            \
      (const __attribute__((address_space(1))) void*)(g),                      \
      (__attribute__((address_space(3))) void*)(l), 16, 0, 0)

// ---------------------------------------------------------------------------
// Elementwise 2-level RNE split fp32 -> bf16 hi/mid (layout preserved).
// Still used for W (row-major = B-operand of G-gemm).
// ---------------------------------------------------------------------------
__global__ __launch_bounds__(256) void esplit2(const float* __restrict__ X,
                                               unsigned short* __restrict__ X1,
                                               unsigned short* __restrict__ X2,
                                               int n4) {
  int i = blockIdx.x * 256 + threadIdx.x;  // handles 4 floats
  if (i >= n4) return;
  float4 v = ((const float4*)X)[i];
  float x[4] = {v.x, v.y, v.z, v.w};
  ushort4 o1, o2;
  unsigned short* d1 = (unsigned short*)&o1;
  unsigned short* d2 = (unsigned short*)&o2;
#pragma unroll
  for (int q = 0; q < 4; ++q) {
    unsigned u1 = rne_hi(x[q]);
    float r1 = x[q] - __uint_as_float(u1);
    unsigned u2 = rne_hi(r1);
    d1[q] = (unsigned short)(u1 >> 16);
    d2[q] = (unsigned short)(u2 >> 16);
  }
  ((ushort4*)X1)[i] = o1;
  ((ushort4*)X2)[i] = o2;
}

// ---------------------------------------------------------------------------
// MFMA split GEMM, 3 terms: Y = X @ B (+ bias if non-null).
// Block tile 128(M) x (128*NH)(N), BK=32, 4 waves 2x2 over 128x128 half(s).
// A: fp32, 2-level RNE split in regs. B: pre-split bf16 [n][k].
// SPLIT: epilogue also emits the 2-level RNE split of the output (S1/S2);
// Y write is skipped when Y == nullptr (e.g. G fp32 never materialized).
// MINW: min waves/EU for occupancy (Z-gemm needs 3 -> 3 blocks/CU).
// ---------------------------------------------------------------------------
template <int NH, int MINW, bool SPLIT>
__global__ __launch_bounds__(256, MINW) void gemm_mfma3(
    const float* __restrict__ X, const unsigned short* __restrict__ W1,
    const unsigned short* __restrict__ W2, const float* __restrict__ bias,
    float* __restrict__ Y, unsigned short* __restrict__ S1,
    unsigned short* __restrict__ S2) {
  __shared__ __align__(16) float          As[4][2][128][4];      // 16KB
  __shared__ __align__(16) unsigned short B1[4][128 * NH][8];    // 8/16KB
  __shared__ __align__(16) unsigned short B2[4][128 * NH][8];    // 8/16KB

  const int tid = threadIdx.x;
  const int w = tid >> 6, lane = tid & 63;
  const int ml = lane & 15, kq = lane >> 4;
  const int wm = (w >> 1) * 64, wn = (w & 1) * 64;
  const int col0 = blockIdx.x * (128 * NH), row0 = blockIdx.y * 128;

  frag_cd acc[NH][4][4];
#pragma unroll
  for (int h = 0; h < NH; ++h)
#pragma unroll
    for (int i = 0; i < 4; ++i)
#pragma unroll
      for (int j = 0; j < 4; ++j)
#pragma unroll
        for (int r = 0; r < 4; ++r) acc[h][i][j][r] = 0.f;

  for (int k0 = 0; k0 < DIM; k0 += 32) {
#pragma unroll
    for (int h = 0; h < 2; ++h)
#pragma unroll
      for (int mh = 0; mh < 2; ++mh) {
        const float* g =
            X + (size_t)(row0 + mh * 64 + lane) * DIM + k0 + w * 8 + h * 4;
        GLL16(g, &As[w][h][mh * 64][0]);
      }
#pragma unroll
    for (int t = 0; t < 2 * NH; ++t) {
      const size_t off = (size_t)(col0 + t * 64 + lane) * DIM + k0 + w * 8;
      GLL16(W1 + off, &B1[w][t * 64][0]);
      GLL16(W2 + off, &B2[w][t * 64][0]);
    }
    __syncthreads();

    FAB a1[4], a2[4];
#pragma unroll
    for (int i = 0; i < 4; ++i) {
      int m = wm + i * 16 + ml;
      float4 f0 = *(const float4*)&As[kq][0][m][0];  // k = kq*8 + 0..3
      float4 f1 = *(const float4*)&As[kq][1][m][0];  // k = kq*8 + 4..7
      split2rn(f0.x, f0.y, a1[i].u[0], a2[i].u[0]);
      split2rn(f0.z, f0.w, a1[i].u[1], a2[i].u[1]);
      split2rn(f1.x, f1.y, a1[i].u[2], a2[i].u[2]);
      split2rn(f1.z, f1.w, a1[i].u[3], a2[i].u[3]);
    }
#pragma unroll
    for (int nh = 0; nh < NH; ++nh) {
#pragma unroll
      for (int j = 0; j < 4; ++j) {
        int n = nh * 128 + wn + j * 16 + ml;
        FAB b1, b2;
        *(uint4*)&b1.u[0] = *(const uint4*)&B1[kq][n][0];
        *(uint4*)&b2.u[0] = *(const uint4*)&B2[kq][n][0];
#pragma unroll
        for (int i = 0; i < 4; ++i) {
          acc[nh][i][j] = __builtin_amdgcn_mfma_f32_16x16x32_bf16(
              a1[i].f, b1.f, acc[nh][i][j], 0, 0, 0);
          acc[nh][i][j] = __builtin_amdgcn_mfma_f32_16x16x32_bf16(
              a1[i].f, b2.f, acc[nh][i][j], 0, 0, 0);
          acc[nh][i][j] = __builtin_amdgcn_mfma_f32_16x16x32_bf16(
              a2[i].f, b1.f, acc[nh][i][j], 0, 0, 0);
        }
      }
    }
    __syncthreads();
  }

  // epilogue: C/D layout col=lane&15, row=(lane>>4)*4+reg
#pragma unroll
  for (int nh = 0; nh < NH; ++nh)
#pragma unroll
    for (int j = 0; j < 4; ++j) {
      int col = col0 + nh * 128 + wn + j * 16 + ml;
      float bv = bias ? bias[col] : 0.f;
#pragma unroll
      for (int i = 0; i < 4; ++i) {
        int rowb = row0 + wm + i * 16 + kq * 4;
#pragma unroll
        for (int r = 0; r < 4; ++r) {
          float val = acc[nh][i][j][r] + bv;
          size_t idx = (size_t)(rowb + r) * DIM + col;
          if (Y) Y[idx] = val;
          if (SPLIT) {
            unsigned u1 = rne_hi(val);
            float rr = val - __uint_as_float(u1);
            unsigned u2 = rne_hi(rr);
            S1[idx] = (unsigned short)(u1 >> 16);
            S2[idx] = (unsigned short)(u2 >> 16);
          }
        }
      }
    }
}

// ---------------------------------------------------------------------------
// Batched sim GEMM partials via MFMA split-3, LDS-free, k-split x4.
// Grid (5, 64, 4) = (m-tile, batch, k-chunk); 1280 blocks, 4 waves each.
// All state in NAMED registers (no arrays -> no scratch demotion).
// part[ks][b][320][112]: padded, maskless epilogue (pads never read).
// Also fuses the u = Xq . wb partial dot (A-data already in regs):
// upart[ks][b][320], cross-kq reduced via 2 shuffles.
// ---------------------------------------------------------------------------
#define MFMA3(ACC, A1, A2, BV1, BV2)                                           \
  ACC = __builtin_amdgcn_mfma_f32_16x16x32_bf16(A1.f, BV1.f, ACC, 0, 0, 0);    \
  ACC = __builtin_amdgcn_mfma_f32_16x16x32_bf16(A1.f, BV2.f, ACC, 0, 0, 0);    \
  ACC = __builtin_amdgcn_mfma_f32_16x16x32_bf16(A2.f, BV1.f, ACC, 0, 0, 0)

#define SIMJ(J)                                                                \
  {                                                                            \
    FAB bf1, bf2;                                                              \
    *(uint4*)&bf1.u[0] = *(const uint4*)(z1b + o##J + k0);                     \
    *(uint4*)&bf2.u[0] = *(const uint4*)(z2b + o##J + k0);                     \
    MFMA3(acc##J, a1, a2, bf1, bf2);                                           \
  }

#define STJ(J)                                                                 \
  {                                                                            \
    const int n = J * 16 + ml;                                                 \
    part[pbase + 0 * PCOL + n] = acc##J[0];                                    \
    part[pbase + 1 * PCOL + n] = acc##J[1];                                    \
    part[pbase + 2 * PCOL + n] = acc##J[2];                                    \
    part[pbase + 3 * PCOL + n] = acc##J[3];                                    \
  }

__global__ __launch_bounds__(256) void sim2_part(
    const float* __restrict__ Xq, const unsigned short* __restrict__ Z1,
    const unsigned short* __restrict__ Z2, const float* __restrict__ wb,
    float* __restrict__ part, float* __restrict__ upart) {
  // bijective XCD swizzle over 1280 blocks: each XCD owns 8 whole batches.
  const int wg = blockIdx.x + 5 * blockIdx.y + 320 * blockIdx.z;
  const int swz = (wg & 7) * 160 + (wg >> 3);
  const int b = swz / 20;
  const int r20 = swz % 20;
  const int ks = r20 / 5;   // k-chunk (0..3)
  const int mt = r20 % 5;   // m-tile within batch (0..4)

  const int w = threadIdx.x >> 6, lane = threadIdx.x & 63;
  const int ml = lane & 15, kq = lane >> 4;

  // A row for this lane (clamped; clamped rows land in pad, never read)
  int r = mt * 64 + w * 16 + ml;
  const int rc = r < NQ ? r : NQ - 1;
  const float* aptr = Xq + ((size_t)b * NQ + rc) * DIM + kq * 8;

  // B bases + 7 static element offsets (clamped cols land in pad)
  const unsigned short* z1b = Z1 + (size_t)b * NS * DIM + kq * 8;
  const unsigned short* z2b = Z2 + (size_t)b * NS * DIM + kq * 8;
  const int o0 = (0 * 16 + ml) * DIM;
  const int o1 = (1 * 16 + ml) * DIM;
  const int o2 = (2 * 16 + ml) * DIM;
  const int o3 = (3 * 16 + ml) * DIM;
  const int o4 = (4 * 16 + ml) * DIM;
  const int o5 = (5 * 16 + ml) * DIM;
  const int n6 = 6 * 16 + ml;
  const int o6 = (n6 < NS ? n6 : NS - 1) * DIM;

  frag_cd acc0 = {0.f, 0.f, 0.f, 0.f}, acc1 = {0.f, 0.f, 0.f, 0.f};
  frag_cd acc2 = {0.f, 0.f, 0.f, 0.f}, acc3 = {0.f, 0.f, 0.f, 0.f};
  frag_cd acc4 = {0.f, 0.f, 0.f, 0.f}, acc5 = {0.f, 0.f, 0.f, 0.f};
  frag_cd acc6 = {0.f, 0.f, 0.f, 0.f};
  float up = 0.f;  // partial u = Xq_row . wb over this k-chunk (this lane's k)

  const int kbeg = ks * (DIM / KSPL), kend = kbeg + DIM / KSPL;
#pragma unroll 2
  for (int k0 = kbeg; k0 < kend; k0 += 32) {
    float4 f0 = *(const float4*)(aptr + k0);      // k = kq*8 + 0..3
    float4 f1 = *(const float4*)(aptr + k0 + 4);  // k = kq*8 + 4..7
    float4 wa = *(const float4*)(wb + k0 + kq * 8);
    float4 wc = *(const float4*)(wb + k0 + kq * 8 + 4);
    up += f0.x * wa.x + f0.y * wa.y + f0.z * wa.z + f0.w * wa.w +
          f1.x * wc.x + f1.y * wc.y + f1.z * wc.z + f1.w * wc.w;
    FAB a1, a2;
    split2rn(f0.x, f0.y, a1.u[0], a2.u[0]);
    split2rn(f0.z, f0.w, a1.u[1], a2.u[1]);
    split2rn(f1.x, f1.y, a1.u[2], a2.u[2]);
    split2rn(f1.z, f1.w, a1.u[3], a2.u[3]);
    SIMJ(0); SIMJ(1); SIMJ(2); SIMJ(3); SIMJ(4); SIMJ(5); SIMJ(6);
  }

  // cross-kq reduce u partial (4 lanes per row: lane = kq*16 + ml)
  up += __shfl_xor(up, 16, 64);
  up += __shfl_xor(up, 32, 64);
  if (lane < 16)
    upart[((size_t)ks * BATCH + b) * PROW + mt * 64 + w * 16 + ml] = up;

  // epilogue: C/D layout col=lane&15, row=(lane>>4)*4+reg; maskless.
  const size_t pbase =
      (((size_t)ks * BATCH + b) * PROW + (mt * 64 + w * 16 + kq * 4)) * PCOL;
  STJ(0); STJ(1); STJ(2); STJ(3); STJ(4); STJ(5); STJ(6);
}

// ---------------------------------------------------------------------------
// wb[k] = sum_n W[k][n] * b[n]; block 0 also computes bb = sum b^2
// ---------------------------------------------------------------------------
__global__ __launch_bounds__(256) void gemv_wb(const float* __restrict__ W,
                                               const float* __restrict__ b,
                                               float* __restrict__ wb,
                                               float* __restrict__ bb) {
  const int k = blockIdx.x;
  const int d0 = threadIdx.x * 8;
  float4 w0 = *(const float4*)(W + (size_t)k * DIM + d0);
  float4 w1 = *(const float4*)(W + (size_t)k * DIM + d0 + 4);
  float4 b0 = *(const float4*)(b + d0);
  float4 b1 = *(const float4*)(b + d0 + 4);
  float s = w0.x * b0.x + w0.y * b0.y + w0.z * b0.z + w0.w * b0.w +
            w1.x * b1.x + w1.y * b1.y + w1.z * b1.z + w1.w * b1.w;
#pragma unroll
  for (int off = 32; off; off >>= 1) s += __shfl_down(s, off, 64);
  __shared__ float red[4];
  if ((threadIdx.x & 63) == 0) red[threadIdx.x >> 6] = s;
  __syncthreads();
  if (threadIdx.x == 0) wb[k] = red[0] + red[1] + red[2] + red[3];
  if (k == 0) {
    float s2 = b0.x * b0.x + b0.y * b0.y + b0.z * b0.z + b0.w * b0.w +
               b1.x * b1.x + b1.y * b1.y + b1.z * b1.z + b1.w * b1.w;
#pragma unroll
    for (int off = 32; off; off >>= 1) s2 += __shfl_down(s2, off, 64);
    __syncthreads();
    if ((threadIdx.x & 63) == 0) red[threadIdx.x >> 6] = s2;
    __syncthreads();
    if (threadIdx.x == 0) bb[0] = red[0] + red[1] + red[2] + red[3];
  }
}

// ---------------------------------------------------------------------------
// ||s_n||^2 = Z_n.Xs_n + 2*Xs_n.wb + bb ; outputs inv_norm and v = Xs_n.wb
// ---------------------------------------------------------------------------
__global__ __launch_bounds__(256) void norm_v(const float* __restrict__ Z,
                                              const float* __restrict__ Xs,
                                              const float* __restrict__ wb,
                                              const float* __restrict__ bb,
                                              float* __restrict__ inv_norm,
                                              float* __restrict__ vv) {
  const int row = blockIdx.x;
  const int d0 = threadIdx.x * 8;
  const float* zp = Z + (size_t)row * DIM + d0;
  const float* xp = Xs + (size_t)row * DIM + d0;
  float4 z0 = *(const float4*)zp, z1 = *(const float4*)(zp + 4);
  float4 x0 = *(const float4*)xp, x1 = *(const float4*)(xp + 4);
  float4 w0 = *(const float4*)(wb + d0), w1 = *(const float4*)(wb + d0 + 4);
  float s1 = z0.x * x0.x + z0.y * x0.y + z0.z * x0.z + z0.w * x0.w +
             z1.x * x1.x + z1.y * x1.y + z1.z * x1.z + z1.w * x1.w;
  float s2 = x0.x * w0.x + x0.y * w0.y + x0.z * w0.z + x0.w * w0.w +
             x1.x * w1.x + x1.y * w1.y + x1.z * w1.z + x1.w * w1.w;
#pragma unroll
  for (int off = 32; off; off >>= 1) {
    s1 += __shfl_down(s1, off, 64);
    s2 += __shfl_down(s2, off, 64);
  }
  __shared__ float r1[4], r2[4];
  if ((threadIdx.x & 63) == 0) {
    r1[threadIdx.x >> 6] = s1;
    r2[threadIdx.x >> 6] = s2;
  }
  __syncthreads();
  if (threadIdx.x == 0) {
    float t1 = r1[0] + r1[1] + r1[2] + r1[3];
    float t2 = r2[0] + r2[1] + r2[2] + r2[3];
    float nn = t1 + 2.f * t2 + bb[0];
    inv_norm[row] = rsqrtf(fmaxf(nn, 1e-10f));
    vv[row] = t2;
  }
}

// ---------------------------------------------------------------------------
// 4-way partial sum + affine + softmax(100) -> one-hot contract (20)
// -> probs + argmax(pred as float)
// ---------------------------------------------------------------------------
__global__ __launch_bounds__(256) void softmax_part(
    const float* __restrict__ part, const float* __restrict__ upart,
    const float* __restrict__ vv, const float* __restrict__ bb,
    const float* __restrict__ inv_norm, const float* __restrict__ onehot,
    float* __restrict__ out) {
  const int wave = threadIdx.x >> 6;
  const int lane = threadIdx.x & 63;
  const int r = blockIdx.x * 4 + wave;   // global query row
  const int b = r / NQ;
  const int m = r - b * NQ;
  const size_t kstr = (size_t)BATCH * PROW * PCOL;
  const size_t ustr = (size_t)BATCH * PROW;
  const float* p0 = part + ((size_t)b * PROW + m) * PCOL;
  const float* up0 = upart + (size_t)b * PROW + m;
  const float bbv = bb[0];
  const float ur = up0[0] + up0[ustr] + up0[2 * ustr] + up0[3 * ustr];

  // n = lane (always < 100)
  float raw1 = p0[lane] + p0[kstr + lane] + p0[2 * kstr + lane] +
               p0[3 * kstr + lane];
  float v1 = (raw1 + ur + vv[b * NS + lane] + bbv) * inv_norm[b * NS + lane];
  // n = lane + 64 (valid when lane < 36)
  float v2 = -INFINITY;
  if (lane < NS - 64) {
    const int n = lane + 64;
    float raw2 = p0[n] + p0[kstr + n] + p0[2 * kstr + n] + p0[3 * kstr + n];
    v2 = (raw2 + ur + vv[b * NS + n] + bbv) * inv_norm[b * NS + n];
  }
  float mx = fmaxf(v1, v2);
#pragma unroll
  for (int off = 32; off; off >>= 1) mx = fmaxf(mx, __shfl_xor(mx, off, 64));
  float e1 = expf(v1 - mx);
  float e2 = (lane < NS - 64) ? expf(v2 - mx) : 0.f;
  float ssum = e1 + e2;
#pragma unroll
  for (int off = 32; off; off >>= 1) ssum += __shfl_xor(ssum, off, 64);
  float inv = 1.0f / ssum;
  __shared__ float att[4][NS];
  __shared__ float pr[4][NCLS];
  att[wave][lane] = e1 * inv;
  if (lane < NS - 64) att[wave][lane + 64] = e2 * inv;
  __syncthreads();
  if (lane < NCLS) {
    const float* oh = onehot + ((size_t)b * NS) * NCLS + lane;
    float p = 0.f;
#pragma unroll 4
    for (int j = 0; j < NS; ++j) p += att[wave][j] * oh[(size_t)j * NCLS];
    out[(size_t)r * NCLS + lane] = p;
    pr[wave][lane] = p;
  }
  __syncthreads();
  if (lane == 0) {
    int best = 0;
    float bv = pr[wave][0];
    for (int c = 1; c < NCLS; ++c) {
      float v = pr[wave][c];
      if (v > bv) { bv = v; best = c; }
    }
    out[(size_t)MQ * NCLS + r] = (float)best;
  }
}

// ---------------------------------------------------------------------------
// Fallback softmax on materialized sim (small-ws path).
// ---------------------------------------------------------------------------
__global__ __launch_bounds__(256) void softmax_fb(
    const float* __restrict__ sim, const float* __restrict__ onehot,
    float* __restrict__ out) {
  const int wave = threadIdx.x >> 6;
  const int lane = threadIdx.x & 63;
  const int r = blockIdx.x * 4 + wave;
  const int b = r / NQ;
  const float* srow = sim + (size_t)r * NS;
  float v1 = srow[lane];
  float v2 = (lane < NS - 64) ? srow[lane + 64] : -INFINITY;
  float m = fmaxf(v1, v2);
#pragma unroll
  for (int off = 32; off; off >>= 1) m = fmaxf(m, __shfl_xor(m, off, 64));
  float e1 = expf(v1 - m);
  float e2 = (lane < NS - 64) ? expf(v2 - m) : 0.f;
  float ssum = e1 + e2;
#pragma unroll
  for (int off = 32; off; off >>= 1) ssum += __shfl_xor(ssum, off, 64);
  float inv = 1.0f / ssum;
  __shared__ float att[4][NS];
  __shared__ float pr[4][NCLS];
  att[wave][lane] = e1 * inv;
  if (lane < NS - 64) att[wave][lane + 64] = e2 * inv;
  __syncthreads();
  if (lane < NCLS) {
    const float* oh = onehot + ((size_t)b * NS) * NCLS + lane;
    float p = 0.f;
#pragma unroll 4
    for (int j = 0; j < NS; ++j) p += att[wave][j] * oh[(size_t)j * NCLS];
    out[(size_t)r * NCLS + lane] = p;
    pr[wave][lane] = p;
  }
  __syncthreads();
  if (lane == 0) {
    int best = 0;
    float bv = pr[wave][0];
    for (int c = 1; c < NCLS; ++c) {
      float v = pr[wave][c];
      if (v > bv) { bv = v; best = c; }
    }
    out[(size_t)MQ * NCLS + r] = (float)best;
  }
}

// ---------------------------------------------------------------------------
// Fallback fp32 GEMM path kernels (proven R1 path)
// ---------------------------------------------------------------------------
__global__ __launch_bounds__(256) void gemm_xw(const float* __restrict__ X,
                                               const float* __restrict__ W,
                                               const float* __restrict__ bias,
                                               float* __restrict__ Y) {
  __shared__ float As[16][64];
  __shared__ float Bs[16][64];
  const int t = threadIdx.x;
  const int row0 = blockIdx.x * 64;
  const int col0 = blockIdx.y * 64;
  const int am = t >> 2, ak = (t & 3) * 4;
  const int bk = t >> 4, bn = (t & 15) * 4;
  const int tm = (t >> 4) * 4, tn = (t & 15) * 4;
  float acc[4][4] = {};
  for (int k0 = 0; k0 < DIM; k0 += 16) {
    float4 av = *(const float4*)(X + (size_t)(row0 + am) * DIM + k0 + ak);
    As[ak + 0][am] = av.x;
    As[ak + 1][am] = av.y;
    As[ak + 2][am] = av.z;
    As[ak + 3][am] = av.w;
    *(float4*)&Bs[bk][bn] =
        *(const float4*)(W + (size_t)(k0 + bk) * DIM + col0 + bn);
    __syncthreads();
#pragma unroll
    for (int k = 0; k < 16; ++k) {
      float4 a4 = *(const float4*)&As[k][tm];
      float4 b4 = *(const float4*)&Bs[k][tn];
      float av_[4] = {a4.x, a4.y, a4.z, a4.w};
      float bv_[4] = {b4.x, b4.y, b4.z, b4.w};
#pragma unroll
      for (int i = 0; i < 4; ++i)
#pragma unroll
        for (int j = 0; j < 4; ++j) acc[i][j] += av_[i] * bv_[j];
    }
    __syncthreads();
  }
  float4 bbv = *(const float4*)(bias + col0 + tn);
  float bv_[4] = {bbv.x, bbv.y, bbv.z, bbv.w};
#pragma unroll
  for (int i = 0; i < 4; ++i) {
    float4 o;
    o.x = acc[i][0] + bv_[0];
    o.y = acc[i][1] + bv_[1];
    o.z = acc[i][2] + bv_[2];
    o.w = acc[i][3] + bv_[3];
    *(float4*)(Y + (size_t)(row0 + tm + i) * DIM + col0 + tn) = o;
  }
}

__global__ __launch_bounds__(256) void norm_kernel(const float* __restrict__ s,
                                                   float* __restrict__ inv_norm) {
  const int row = blockIdx.x;
  const float* p = s + (size_t)row * DIM;
  const int d0 = threadIdx.x * 8;
  float4 a = *(const float4*)(p + d0);
  float4 b = *(const float4*)(p + d0 + 4);
  float sum = a.x * a.x + a.y * a.y + a.z * a.z + a.w * a.w +
              b.x * b.x + b.y * b.y + b.z * b.z + b.w * b.w;
#pragma unroll
  for (int off = 32; off; off >>= 1) sum += __shfl_down(sum, off, 64);
  __shared__ float red[4];
  if ((threadIdx.x & 63) == 0) red[threadIdx.x >> 6] = sum;
  __syncthreads();
  if (threadIdx.x == 0) {
    float tot = red[0] + red[1] + red[2] + red[3];
    inv_norm[row] = rsqrtf(fmaxf(tot, 1e-10f));
  }
}

__global__ __launch_bounds__(256) void sim_kernel(const float* __restrict__ q,
                                                  const float* __restrict__ s,
                                                  const float* __restrict__ inv_norm,
                                                  float* __restrict__ sim) {
  __shared__ float As[16][64];
  __shared__ float Bs[16][64];
  const int t = threadIdx.x;
  const int b = blockIdx.z;
  const int row0 = blockIdx.y * 64;
  const int col0 = blockIdx.x * 64;
  const float* qb = q + (size_t)b * NQ * DIM;
  const float* sb = s + (size_t)b * NS * DIM;
  const int am = t >> 2, ak = (t & 3) * 4;
  const int tm = (t >> 4) * 4, tn = (t & 15) * 4;
  float acc[4][4] = {};
  for (int k0 = 0; k0 < DIM; k0 += 16) {
    float4 av = make_float4(0.f, 0.f, 0.f, 0.f);
    if (row0 + am < NQ)
      av = *(const float4*)(qb + (size_t)(row0 + am) * DIM + k0 + ak);
    As[ak + 0][am] = av.x;
    As[ak + 1][am] = av.y;
    As[ak + 2][am] = av.z;
    As[ak + 3][am] = av.w;
    float4 bv = make_float4(0.f, 0.f, 0.f, 0.f);
    if (col0 + am < NS)
      bv = *(const float4*)(sb + (size_t)(col0 + am) * DIM + k0 + ak);
    Bs[ak + 0][am] = bv.x;
    Bs[ak + 1][am] = bv.y;
    Bs[ak + 2][am] = bv.z;
    Bs[ak + 3][am] = bv.w;
    __syncthreads();
#pragma unroll
    for (int k = 0; k < 16; ++k) {
      float4 a4 = *(const float4*)&As[k][tm];
      float4 b4 = *(const float4*)&Bs[k][tn];
      float av_[4] = {a4.x, a4.y, a4.z, a4.w};
      float bv_[4] = {b4.x, b4.y, b4.z, b4.w};
#pragma unroll
      for (int i = 0; i < 4; ++i)
#pragma unroll
        for (int j = 0; j < 4; ++j) acc[i][j] += av_[i] * bv_[j];
    }
    __syncthreads();
  }
#pragma unroll
  for (int i = 0; i < 4; ++i) {
    int m = row0 + tm + i;
    if (m >= NQ) continue;
#pragma unroll
    for (int j = 0; j < 4; ++j) {
      int n = col0 + tn + j;
      if (n >= NS) continue;
      sim[((size_t)b * NQ + m) * NS + n] = acc[i][j] * inv_norm[b * NS + n];
    }
  }
}

// ---------------------------------------------------------------------------
extern "C" void kernel_launch(void* const* d_in, const int* in_sizes, int n_in,
                              void* d_out, int out_size, void* d_ws,
                              size_t ws_size, hipStream_t stream) {
  const float* support = (const float*)d_in[0];
  const float* query   = (const float*)d_in[1];
  const float* onehot  = (const float*)d_in[2];
  const float* W       = (const float*)d_in[3];
  const float* bias    = (const float*)d_in[4];

  char* wsb = (char*)d_ws;

  // --- Gram-matrix path workspace layout ---
  // Z    : 6400*2048*4      = 52,428,800   @ 0
  // (G fp32 eliminated; region 52,428,800.. reused by part)
  // Wr1  : 2048*2048*2      =  8,388,608   @ 69,206,016  (dead after G-gemm)
  // Wr2  :                  =  8,388,608   @ 77,594,624  (dead after G-gemm)
  // G1   :                  =  8,388,608   @ 85,983,232  (dead after Z-gemm)
  // G2   :                  =  8,388,608   @ 94,371,840  (dead after Z-gemm)
  // Z1   : 6400*2048*2      = 26,214,400   @ 102,760,448
  // Z2   :                  = 26,214,400   @ 128,974,848
  // part : 4*64*320*112*4   = 36,700,160   @ 52,428,800  (overlays dead Wr/G1/G2)
  // inv  :  6400*4          =     25,600   @ 162,869,248
  // vv   :  6400*4          =     25,600   @ 162,894,848
  // wb   :  2048*4          =      8,192   @ 162,997,248
  // bb   :      4                          @ 163,005,440
  // upart: 4*64*320*4       =    327,680   @ 163,005,696
  const size_t NEED = 163333376;

  if (ws_size >= NEED) {
    float* Z              = (float*)wsb;
    unsigned short* Wr1   = (unsigned short*)(wsb + (size_t)69206016);
    unsigned short* Wr2   = (unsigned short*)(wsb + (size_t)77594624);
    unsigned short* G1    = (unsigned short*)(wsb + (size_t)85983232);
    unsigned short* G2    = (unsigned short*)(wsb + (size_t)94371840);
    unsigned short* Z1    = (unsigned short*)(wsb + (size_t)102760448);
    unsigned short* Z2    = (unsigned short*)(wsb + (size_t)128974848);
    float* part           = (float*)(wsb + (size_t)52428800);
    float* inv_norm       = (float*)(wsb + (size_t)162869248);
    float* vv             = (float*)(wsb + (size_t)162894848);
    float* wb             = (float*)(wsb + (size_t)162997248);
    float* bb             = (float*)(wsb + (size_t)163005440);
    float* upart          = (float*)(wsb + (size_t)163005696);

    // W splits (row-major W = simultaneously A and the B-operand of G-gemm)
    esplit2<<<DIM * DIM / 1024, 256, 0, stream>>>(W, Wr1, Wr2, DIM * DIM / 4);
    // G = W @ W^T: fused epilogue writes G1/G2 directly (no G fp32).
    // G symmetric -> its row-major split is its own [n][k] split.
    gemm_mfma3<1, 3, true><<<dim3(DIM / 128, DIM / 128), 256, 0, stream>>>(
        W, Wr1, Wr2, nullptr, nullptr, G1, G2);
    // Z = Xs @ G: NH=1 tile (800 blocks, 3 blocks/CU) + fused Z1/Z2 split.
    gemm_mfma3<1, 3, true><<<dim3(DIM / 128, MS / 128), 256, 0, stream>>>(
        support, G1, G2, nullptr, Z, Z1, Z2);
    // bias terms: wb = W@b, bb = ||b||^2, v = Xs@wb (fused in norm_v)
    gemv_wb<<<DIM, 256, 0, stream>>>(W, bias, wb, bb);
    norm_v<<<MS, 256, 0, stream>>>(Z, support, wb, bb, inv_norm, vv);
    // sim partials (k-split x4, MFMA, LDS-free) + fused u = Xq.wb partials
    sim2_part<<<dim3(5, BATCH, KSPL), 256, 0, stream>>>(query, Z1, Z2, wb,
                                                        part, upart);
    // partial-sum + affine + softmax + onehot contract + argmax
    softmax_part<<<MQ / 4, 256, 0, stream>>>(part, upart, vv, bb, inv_norm,
                                             onehot, (float*)d_out);
  } else {
    // proven R1 fallback (fits in 217.5 MB)
    float* s = (float*)wsb;
    float* q = (float*)(wsb + (size_t)52428800);
    float* inv_norm = q + (size_t)MQ * DIM;
    float* sim      = inv_norm + MS;
    gemm_xw<<<dim3(MS / 64, DIM / 64), 256, 0, stream>>>(support, W, bias, s);
    gemm_xw<<<dim3(MQ / 64, DIM / 64), 256, 0, stream>>>(query, W, bias, q);
    norm_kernel<<<MS, 256, 0, stream>>>(s, inv_norm);
    sim_kernel<<<dim3(2, 5, BATCH), 256, 0, stream>>>(q, s, inv_norm, sim);
    softmax_fb<<<MQ / 4, 256, 0, stream>>>(sim, onehot, (float*)d_out);
  }
}

// Round 5
// 747.767 us; speedup vs baseline: 1.2075x; 1.2075x over previous
//
#include <hip/hip_runtime.h>
#include <hip/hip_bf16.h>
#include <math.h>

// Problem constants: B=64, C=20, K=5, Q=15, D=2048
#define BATCH 64
#define NCLS  20
#define NS    100   // C*K
#define NQ    300   // C*Q
#define DIM   2048
#define MS    (BATCH * NS)   // 6400
#define MQ    (BATCH * NQ)   // 19200
#define KSPL  4              // k-split factor for sim GEMM
#define PROW  320            // padded rows per batch in partial buffer
#define PCOL  112            // padded cols per batch in partial buffer

typedef __attribute__((ext_vector_type(8))) short frag_ab;   // 8 bf16 (4 VGPRs)
typedef __attribute__((ext_vector_type(4))) float frag_cd;   // 4 fp32 acc

union FAB { frag_ab f; unsigned u[4]; };

// round-to-nearest-even bf16 hi part, returned as fp32 bit pattern
__device__ __forceinline__ unsigned rne_hi(float x) {
  unsigned u = __float_as_uint(x);
  return (u + 0x7FFFu + ((u >> 16) & 1u)) & 0xFFFF0000u;
}

// 2-level RNE split of pair (x,y): x ~= x1 + x2, |residual| <= 2^-18|x|.
__device__ __forceinline__ void split2rn(float x, float y, unsigned& p1,
                                         unsigned& p2) {
  union { __hip_bfloat162 h; unsigned u; } c1, c2;
  c1.h = __float22bfloat162_rn(make_float2(x, y));
  p1 = c1.u;
  float rx = x - __uint_as_float(c1.u << 16);
  float ry = y - __uint_as_float(c1.u & 0xFFFF0000u);
  c2.h = __float22bfloat162_rn(make_float2(rx, ry));
  p2 = c2.u;
}

#define GLL16(g, l)                                                            \
  __builtin_amdgcn_global_load_lds(                                            \
      (const __attribute__((address_space(1))) void*)(g),                      \
      (__attribute__((address_space(3))) void*)(l), 16, 0, 0)

// ---------------------------------------------------------------------------
// Elementwise 2-level RNE split fp32 -> bf16 hi/mid (layout preserved).
// Used for W and support (row-major [row][k] = A/B operand layouts).
// ---------------------------------------------------------------------------
__global__ __launch_bounds__(256) void esplit2(const float* __restrict__ X,
                                               unsigned short* __restrict__ X1,
                                               unsigned short* __restrict__ X2,
                                               int n4) {
  int i = blockIdx.x * 256 + threadIdx.x;  // handles 4 floats
  if (i >= n4) return;
  float4 v = ((const float4*)X)[i];
  float x[4] = {v.x, v.y, v.z, v.w};
  ushort4 o1, o2;
  unsigned short* d1 = (unsigned short*)&o1;
  unsigned short* d2 = (unsigned short*)&o2;
#pragma unroll
  for (int q = 0; q < 4; ++q) {
    unsigned u1 = rne_hi(x[q]);
    float r1 = x[q] - __uint_as_float(u1);
    unsigned u2 = rne_hi(r1);
    d1[q] = (unsigned short)(u1 >> 16);
    d2[q] = (unsigned short)(u2 >> 16);
  }
  ((ushort4*)X1)[i] = o1;
  ((ushort4*)X2)[i] = o2;
}

// ---------------------------------------------------------------------------
// All-bf16 pre-split MFMA GEMM, 3 terms: Y = (A1+A2) @ (B1+B2)^T-ish where
// A1/A2 [m][k], B1/B2 [n][k] are 2-level RNE splits. Terms a1b1+a1b2+a2b1.
// No in-loop split VALU (the R4 counter lesson: 16 split2rn/k-tile ~= half
// the MFMA time). Block tile 128(M) x (128*NH)(N), BK=32, 4 waves 2x2.
// Epilogue: optional fp32 Y write + fused 2-level RNE split S1o/S2o
// (value-identical to a separate esplit2 pass; proven in R4).
// ---------------------------------------------------------------------------
template <int NH, int MINW>
__global__ __launch_bounds__(256, MINW) void gemm_bb3(
    const unsigned short* __restrict__ A1, const unsigned short* __restrict__ A2,
    const unsigned short* __restrict__ B1, const unsigned short* __restrict__ B2,
    float* __restrict__ Y, unsigned short* __restrict__ S1o,
    unsigned short* __restrict__ S2o) {
  __shared__ __align__(16) unsigned short A1s[4][128][8];        // 8KB
  __shared__ __align__(16) unsigned short A2s[4][128][8];        // 8KB
  __shared__ __align__(16) unsigned short B1s[4][128 * NH][8];   // 8/16KB
  __shared__ __align__(16) unsigned short B2s[4][128 * NH][8];   // 8/16KB

  const int tid = threadIdx.x;
  const int w = tid >> 6, lane = tid & 63;
  const int ml = lane & 15, kq = lane >> 4;
  const int wm = (w >> 1) * 64, wn = (w & 1) * 64;
  const int col0 = blockIdx.x * (128 * NH), row0 = blockIdx.y * 128;

  frag_cd acc[NH][4][4];
#pragma unroll
  for (int h = 0; h < NH; ++h)
#pragma unroll
    for (int i = 0; i < 4; ++i)
#pragma unroll
      for (int j = 0; j < 4; ++j)
#pragma unroll
        for (int r = 0; r < 4; ++r) acc[h][i][j][r] = 0.f;

  for (int k0 = 0; k0 < DIM; k0 += 32) {
    // ---- stage A (2 splits x 2 row-halves): wave w covers k=k0+w*8..+7 ----
#pragma unroll
    for (int mh = 0; mh < 2; ++mh) {
      const size_t off = (size_t)(row0 + mh * 64 + lane) * DIM + k0 + w * 8;
      GLL16(A1 + off, &A1s[w][mh * 64][0]);
      GLL16(A2 + off, &A2s[w][mh * 64][0]);
    }
    // ---- stage B (2 splits x 128*NH cols) ----
#pragma unroll
    for (int t = 0; t < 2 * NH; ++t) {
      const size_t off = (size_t)(col0 + t * 64 + lane) * DIM + k0 + w * 8;
      GLL16(B1 + off, &B1s[w][t * 64][0]);
      GLL16(B2 + off, &B2s[w][t * 64][0]);
    }
    __syncthreads();

    // ---- A frags: straight 16B LDS reads, no split math ----
    FAB a1[4], a2[4];
#pragma unroll
    for (int i = 0; i < 4; ++i) {
      int m = wm + i * 16 + ml;
      *(uint4*)&a1[i].u[0] = *(const uint4*)&A1s[kq][m][0];
      *(uint4*)&a2[i].u[0] = *(const uint4*)&A2s[kq][m][0];
    }
    // ---- NH column halves x 16 frag-pairs x 3 MFMA terms ----
#pragma unroll
    for (int nh = 0; nh < NH; ++nh) {
#pragma unroll
      for (int j = 0; j < 4; ++j) {
        int n = nh * 128 + wn + j * 16 + ml;
        FAB b1, b2;
        *(uint4*)&b1.u[0] = *(const uint4*)&B1s[kq][n][0];
        *(uint4*)&b2.u[0] = *(const uint4*)&B2s[kq][n][0];
#pragma unroll
        for (int i = 0; i < 4; ++i) {
          acc[nh][i][j] = __builtin_amdgcn_mfma_f32_16x16x32_bf16(
              a1[i].f, b1.f, acc[nh][i][j], 0, 0, 0);
          acc[nh][i][j] = __builtin_amdgcn_mfma_f32_16x16x32_bf16(
              a1[i].f, b2.f, acc[nh][i][j], 0, 0, 0);
          acc[nh][i][j] = __builtin_amdgcn_mfma_f32_16x16x32_bf16(
              a2[i].f, b1.f, acc[nh][i][j], 0, 0, 0);
        }
      }
    }
    __syncthreads();
  }

  // epilogue: C/D layout col=lane&15, row=(lane>>4)*4+reg; fused split.
#pragma unroll
  for (int nh = 0; nh < NH; ++nh)
#pragma unroll
    for (int j = 0; j < 4; ++j) {
      int col = col0 + nh * 128 + wn + j * 16 + ml;
#pragma unroll
      for (int i = 0; i < 4; ++i) {
        int rowb = row0 + wm + i * 16 + kq * 4;
#pragma unroll
        for (int r = 0; r < 4; ++r) {
          float val = acc[nh][i][j][r];
          size_t idx = (size_t)(rowb + r) * DIM + col;
          if (Y) Y[idx] = val;
          unsigned u1 = rne_hi(val);
          float rr = val - __uint_as_float(u1);
          unsigned u2 = rne_hi(rr);
          S1o[idx] = (unsigned short)(u1 >> 16);
          S2o[idx] = (unsigned short)(u2 >> 16);
        }
      }
    }
}

// ---------------------------------------------------------------------------
// Batched sim GEMM partials via MFMA split-3, LDS-free, k-split x4.
// Grid (5, 64, 4) = (m-tile, batch, k-chunk); 1280 blocks, 4 waves each.
// All state in NAMED registers (no arrays -> no scratch demotion).
// part[ks][b][320][112]: padded, maskless epilogue (pads never read).
// Also fuses the u = Xq . wb partial dot (A-data already in regs):
// upart[ks][b][320], cross-kq reduced via 2 shuffles.
// ---------------------------------------------------------------------------
#define MFMA3(ACC, A1, A2, BV1, BV2)                                           \
  ACC = __builtin_amdgcn_mfma_f32_16x16x32_bf16(A1.f, BV1.f, ACC, 0, 0, 0);    \
  ACC = __builtin_amdgcn_mfma_f32_16x16x32_bf16(A1.f, BV2.f, ACC, 0, 0, 0);    \
  ACC = __builtin_amdgcn_mfma_f32_16x16x32_bf16(A2.f, BV1.f, ACC, 0, 0, 0)

#define SIMJ(J)                                                                \
  {                                                                            \
    FAB bf1, bf2;                                                              \
    *(uint4*)&bf1.u[0] = *(const uint4*)(z1b + o##J + k0);                     \
    *(uint4*)&bf2.u[0] = *(const uint4*)(z2b + o##J + k0);                     \
    MFMA3(acc##J, a1, a2, bf1, bf2);                                           \
  }

#define STJ(J)                                                                 \
  {                                                                            \
    const int n = J * 16 + ml;                                                 \
    part[pbase + 0 * PCOL + n] = acc##J[0];                                    \
    part[pbase + 1 * PCOL + n] = acc##J[1];                                    \
    part[pbase + 2 * PCOL + n] = acc##J[2];                                    \
    part[pbase + 3 * PCOL + n] = acc##J[3];                                    \
  }

__global__ __launch_bounds__(256) void sim2_part(
    const float* __restrict__ Xq, const unsigned short* __restrict__ Z1,
    const unsigned short* __restrict__ Z2, const float* __restrict__ wb,
    float* __restrict__ part, float* __restrict__ upart) {
  // bijective XCD swizzle over 1280 blocks: each XCD owns 8 whole batches.
  const int wg = blockIdx.x + 5 * blockIdx.y + 320 * blockIdx.z;
  const int swz = (wg & 7) * 160 + (wg >> 3);
  const int b = swz / 20;
  const int r20 = swz % 20;
  const int ks = r20 / 5;   // k-chunk (0..3)
  const int mt = r20 % 5;   // m-tile within batch (0..4)

  const int w = threadIdx.x >> 6, lane = threadIdx.x & 63;
  const int ml = lane & 15, kq = lane >> 4;

  // A row for this lane (clamped; clamped rows land in pad, never read)
  int r = mt * 64 + w * 16 + ml;
  const int rc = r < NQ ? r : NQ - 1;
  const float* aptr = Xq + ((size_t)b * NQ + rc) * DIM + kq * 8;

  // B bases + 7 static element offsets (clamped cols land in pad)
  const unsigned short* z1b = Z1 + (size_t)b * NS * DIM + kq * 8;
  const unsigned short* z2b = Z2 + (size_t)b * NS * DIM + kq * 8;
  const int o0 = (0 * 16 + ml) * DIM;
  const int o1 = (1 * 16 + ml) * DIM;
  const int o2 = (2 * 16 + ml) * DIM;
  const int o3 = (3 * 16 + ml) * DIM;
  const int o4 = (4 * 16 + ml) * DIM;
  const int o5 = (5 * 16 + ml) * DIM;
  const int n6 = 6 * 16 + ml;
  const int o6 = (n6 < NS ? n6 : NS - 1) * DIM;

  frag_cd acc0 = {0.f, 0.f, 0.f, 0.f}, acc1 = {0.f, 0.f, 0.f, 0.f};
  frag_cd acc2 = {0.f, 0.f, 0.f, 0.f}, acc3 = {0.f, 0.f, 0.f, 0.f};
  frag_cd acc4 = {0.f, 0.f, 0.f, 0.f}, acc5 = {0.f, 0.f, 0.f, 0.f};
  frag_cd acc6 = {0.f, 0.f, 0.f, 0.f};
  float up = 0.f;  // partial u = Xq_row . wb over this k-chunk (this lane's k)

  const int kbeg = ks * (DIM / KSPL), kend = kbeg + DIM / KSPL;
#pragma unroll 2
  for (int k0 = kbeg; k0 < kend; k0 += 32) {
    float4 f0 = *(const float4*)(aptr + k0);      // k = kq*8 + 0..3
    float4 f1 = *(const float4*)(aptr + k0 + 4);  // k = kq*8 + 4..7
    float4 wa = *(const float4*)(wb + k0 + kq * 8);
    float4 wc = *(const float4*)(wb + k0 + kq * 8 + 4);
    up += f0.x * wa.x + f0.y * wa.y + f0.z * wa.z + f0.w * wa.w +
          f1.x * wc.x + f1.y * wc.y + f1.z * wc.z + f1.w * wc.w;
    FAB a1, a2;
    split2rn(f0.x, f0.y, a1.u[0], a2.u[0]);
    split2rn(f0.z, f0.w, a1.u[1], a2.u[1]);
    split2rn(f1.x, f1.y, a1.u[2], a2.u[2]);
    split2rn(f1.z, f1.w, a1.u[3], a2.u[3]);
    SIMJ(0); SIMJ(1); SIMJ(2); SIMJ(3); SIMJ(4); SIMJ(5); SIMJ(6);
  }

  // cross-kq reduce u partial (4 lanes per row: lane = kq*16 + ml)
  up += __shfl_xor(up, 16, 64);
  up += __shfl_xor(up, 32, 64);
  if (lane < 16)
    upart[((size_t)ks * BATCH + b) * PROW + mt * 64 + w * 16 + ml] = up;

  // epilogue: C/D layout col=lane&15, row=(lane>>4)*4+reg; maskless.
  const size_t pbase =
      (((size_t)ks * BATCH + b) * PROW + (mt * 64 + w * 16 + kq * 4)) * PCOL;
  STJ(0); STJ(1); STJ(2); STJ(3); STJ(4); STJ(5); STJ(6);
}

// ---------------------------------------------------------------------------
// wb[k] = sum_n W[k][n] * b[n]; block 0 also computes bb = sum b^2
// ---------------------------------------------------------------------------
__global__ __launch_bounds__(256) void gemv_wb(const float* __restrict__ W,
                                               const float* __restrict__ b,
                                               float* __restrict__ wb,
                                               float* __restrict__ bb) {
  const int k = blockIdx.x;
  const int d0 = threadIdx.x * 8;
  float4 w0 = *(const float4*)(W + (size_t)k * DIM + d0);
  float4 w1 = *(const float4*)(W + (size_t)k * DIM + d0 + 4);
  float4 b0 = *(const float4*)(b + d0);
  float4 b1 = *(const float4*)(b + d0 + 4);
  float s = w0.x * b0.x + w0.y * b0.y + w0.z * b0.z + w0.w * b0.w +
            w1.x * b1.x + w1.y * b1.y + w1.z * b1.z + w1.w * b1.w;
#pragma unroll
  for (int off = 32; off; off >>= 1) s += __shfl_down(s, off, 64);
  __shared__ float red[4];
  if ((threadIdx.x & 63) == 0) red[threadIdx.x >> 6] = s;
  __syncthreads();
  if (threadIdx.x == 0) wb[k] = red[0] + red[1] + red[2] + red[3];
  if (k == 0) {
    float s2 = b0.x * b0.x + b0.y * b0.y + b0.z * b0.z + b0.w * b0.w +
               b1.x * b1.x + b1.y * b1.y + b1.z * b1.z + b1.w * b1.w;
#pragma unroll
    for (int off = 32; off; off >>= 1) s2 += __shfl_down(s2, off, 64);
    __syncthreads();
    if ((threadIdx.x & 63) == 0) red[threadIdx.x >> 6] = s2;
    __syncthreads();
    if (threadIdx.x == 0) bb[0] = red[0] + red[1] + red[2] + red[3];
  }
}

// ---------------------------------------------------------------------------
// ||s_n||^2 = Z_n.Xs_n + 2*Xs_n.wb + bb ; outputs inv_norm and v = Xs_n.wb
// ---------------------------------------------------------------------------
__global__ __launch_bounds__(256) void norm_v(const float* __restrict__ Z,
                                              const float* __restrict__ Xs,
                                              const float* __restrict__ wb,
                                              const float* __restrict__ bb,
                                              float* __restrict__ inv_norm,
                                              float* __restrict__ vv) {
  const int row = blockIdx.x;
  const int d0 = threadIdx.x * 8;
  const float* zp = Z + (size_t)row * DIM + d0;
  const float* xp = Xs + (size_t)row * DIM + d0;
  float4 z0 = *(const float4*)zp, z1 = *(const float4*)(zp + 4);
  float4 x0 = *(const float4*)xp, x1 = *(const float4*)(xp + 4);
  float4 w0 = *(const float4*)(wb + d0), w1 = *(const float4*)(wb + d0 + 4);
  float s1 = z0.x * x0.x + z0.y * x0.y + z0.z * x0.z + z0.w * x0.w +
             z1.x * x1.x + z1.y * x1.y + z1.z * x1.z + z1.w * x1.w;
  float s2 = x0.x * w0.x + x0.y * w0.y + x0.z * w0.z + x0.w * w0.w +
             x1.x * w1.x + x1.y * w1.y + x1.z * w1.z + x1.w * w1.w;
#pragma unroll
  for (int off = 32; off; off >>= 1) {
    s1 += __shfl_down(s1, off, 64);
    s2 += __shfl_down(s2, off, 64);
  }
  __shared__ float r1[4], r2[4];
  if ((threadIdx.x & 63) == 0) {
    r1[threadIdx.x >> 6] = s1;
    r2[threadIdx.x >> 6] = s2;
  }
  __syncthreads();
  if (threadIdx.x == 0) {
    float t1 = r1[0] + r1[1] + r1[2] + r1[3];
    float t2 = r2[0] + r2[1] + r2[2] + r2[3];
    float nn = t1 + 2.f * t2 + bb[0];
    inv_norm[row] = rsqrtf(fmaxf(nn, 1e-10f));
    vv[row] = t2;
  }
}

// ---------------------------------------------------------------------------
// 4-way partial sum + affine + softmax(100) -> one-hot contract (20)
// -> probs + argmax(pred as float)
// ---------------------------------------------------------------------------
__global__ __launch_bounds__(256) void softmax_part(
    const float* __restrict__ part, const float* __restrict__ upart,
    const float* __restrict__ vv, const float* __restrict__ bb,
    const float* __restrict__ inv_norm, const float* __restrict__ onehot,
    float* __restrict__ out) {
  const int wave = threadIdx.x >> 6;
  const int lane = threadIdx.x & 63;
  const int r = blockIdx.x * 4 + wave;   // global query row
  const int b = r / NQ;
  const int m = r - b * NQ;
  const size_t kstr = (size_t)BATCH * PROW * PCOL;
  const size_t ustr = (size_t)BATCH * PROW;
  const float* p0 = part + ((size_t)b * PROW + m) * PCOL;
  const float* up0 = upart + (size_t)b * PROW + m;
  const float bbv = bb[0];
  const float ur = up0[0] + up0[ustr] + up0[2 * ustr] + up0[3 * ustr];

  // n = lane (always < 100)
  float raw1 = p0[lane] + p0[kstr + lane] + p0[2 * kstr + lane] +
               p0[3 * kstr + lane];
  float v1 = (raw1 + ur + vv[b * NS + lane] + bbv) * inv_norm[b * NS + lane];
  // n = lane + 64 (valid when lane < 36)
  float v2 = -INFINITY;
  if (lane < NS - 64) {
    const int n = lane + 64;
    float raw2 = p0[n] + p0[kstr + n] + p0[2 * kstr + n] + p0[3 * kstr + n];
    v2 = (raw2 + ur + vv[b * NS + n] + bbv) * inv_norm[b * NS + n];
  }
  float mx = fmaxf(v1, v2);
#pragma unroll
  for (int off = 32; off; off >>= 1) mx = fmaxf(mx, __shfl_xor(mx, off, 64));
  float e1 = expf(v1 - mx);
  float e2 = (lane < NS - 64) ? expf(v2 - mx) : 0.f;
  float ssum = e1 + e2;
#pragma unroll
  for (int off = 32; off; off >>= 1) ssum += __shfl_xor(ssum, off, 64);
  float inv = 1.0f / ssum;
  __shared__ float att[4][NS];
  __shared__ float pr[4][NCLS];
  att[wave][lane] = e1 * inv;
  if (lane < NS - 64) att[wave][lane + 64] = e2 * inv;
  __syncthreads();
  if (lane < NCLS) {
    const float* oh = onehot + ((size_t)b * NS) * NCLS + lane;
    float p = 0.f;
#pragma unroll 4
    for (int j = 0; j < NS; ++j) p += att[wave][j] * oh[(size_t)j * NCLS];
    out[(size_t)r * NCLS + lane] = p;
    pr[wave][lane] = p;
  }
  __syncthreads();
  if (lane == 0) {
    int best = 0;
    float bv = pr[wave][0];
    for (int c = 1; c < NCLS; ++c) {
      float v = pr[wave][c];
      if (v > bv) { bv = v; best = c; }
    }
    out[(size_t)MQ * NCLS + r] = (float)best;
  }
}

// ---------------------------------------------------------------------------
// Fallback softmax on materialized sim (small-ws path).
// ---------------------------------------------------------------------------
__global__ __launch_bounds__(256) void softmax_fb(
    const float* __restrict__ sim, const float* __restrict__ onehot,
    float* __restrict__ out) {
  const int wave = threadIdx.x >> 6;
  const int lane = threadIdx.x & 63;
  const int r = blockIdx.x * 4 + wave;
  const int b = r / NQ;
  const float* srow = sim + (size_t)r * NS;
  float v1 = srow[lane];
  float v2 = (lane < NS - 64) ? srow[lane + 64] : -INFINITY;
  float m = fmaxf(v1, v2);
#pragma unroll
  for (int off = 32; off; off >>= 1) m = fmaxf(m, __shfl_xor(m, off, 64));
  float e1 = expf(v1 - m);
  float e2 = (lane < NS - 64) ? expf(v2 - m) : 0.f;
  float ssum = e1 + e2;
#pragma unroll
  for (int off = 32; off; off >>= 1) ssum += __shfl_xor(ssum, off, 64);
  float inv = 1.0f / ssum;
  __shared__ float att[4][NS];
  __shared__ float pr[4][NCLS];
  att[wave][lane] = e1 * inv;
  if (lane < NS - 64) att[wave][lane + 64] = e2 * inv;
  __syncthreads();
  if (lane < NCLS) {
    const float* oh = onehot + ((size_t)b * NS) * NCLS + lane;
    float p = 0.f;
#pragma unroll 4
    for (int j = 0; j < NS; ++j) p += att[wave][j] * oh[(size_t)j * NCLS];
    out[(size_t)r * NCLS + lane] = p;
    pr[wave][lane] = p;
  }
  __syncthreads();
  if (lane == 0) {
    int best = 0;
    float bv = pr[wave][0];
    for (int c = 1; c < NCLS; ++c) {
      float v = pr[wave][c];
      if (v > bv) { bv = v; best = c; }
    }
    out[(size_t)MQ * NCLS + r] = (float)best;
  }
}

// ---------------------------------------------------------------------------
// Fallback fp32 GEMM path kernels (proven R1 path)
// ---------------------------------------------------------------------------
__global__ __launch_bounds__(256) void gemm_xw(const float* __restrict__ X,
                                               const float* __restrict__ W,
                                               const float* __restrict__ bias,
                                               float* __restrict__ Y) {
  __shared__ float As[16][64];
  __shared__ float Bs[16][64];
  const int t = threadIdx.x;
  const int row0 = blockIdx.x * 64;
  const int col0 = blockIdx.y * 64;
  const int am = t >> 2, ak = (t & 3) * 4;
  const int bk = t >> 4, bn = (t & 15) * 4;
  const int tm = (t >> 4) * 4, tn = (t & 15) * 4;
  float acc[4][4] = {};
  for (int k0 = 0; k0 < DIM; k0 += 16) {
    float4 av = *(const float4*)(X + (size_t)(row0 + am) * DIM + k0 + ak);
    As[ak + 0][am] = av.x;
    As[ak + 1][am] = av.y;
    As[ak + 2][am] = av.z;
    As[ak + 3][am] = av.w;
    *(float4*)&Bs[bk][bn] =
        *(const float4*)(W + (size_t)(k0 + bk) * DIM + col0 + bn);
    __syncthreads();
#pragma unroll
    for (int k = 0; k < 16; ++k) {
      float4 a4 = *(const float4*)&As[k][tm];
      float4 b4 = *(const float4*)&Bs[k][tn];
      float av_[4] = {a4.x, a4.y, a4.z, a4.w};
      float bv_[4] = {b4.x, b4.y, b4.z, b4.w};
#pragma unroll
      for (int i = 0; i < 4; ++i)
#pragma unroll
        for (int j = 0; j < 4; ++j) acc[i][j] += av_[i] * bv_[j];
    }
    __syncthreads();
  }
  float4 bbv = *(const float4*)(bias + col0 + tn);
  float bv_[4] = {bbv.x, bbv.y, bbv.z, bbv.w};
#pragma unroll
  for (int i = 0; i < 4; ++i) {
    float4 o;
    o.x = acc[i][0] + bv_[0];
    o.y = acc[i][1] + bv_[1];
    o.z = acc[i][2] + bv_[2];
    o.w = acc[i][3] + bv_[3];
    *(float4*)(Y + (size_t)(row0 + tm + i) * DIM + col0 + tn) = o;
  }
}

__global__ __launch_bounds__(256) void norm_kernel(const float* __restrict__ s,
                                                   float* __restrict__ inv_norm) {
  const int row = blockIdx.x;
  const float* p = s + (size_t)row * DIM;
  const int d0 = threadIdx.x * 8;
  float4 a = *(const float4*)(p + d0);
  float4 b = *(const float4*)(p + d0 + 4);
  float sum = a.x * a.x + a.y * a.y + a.z * a.z + a.w * a.w +
              b.x * b.x + b.y * b.y + b.z * b.z + b.w * b.w;
#pragma unroll
  for (int off = 32; off; off >>= 1) sum += __shfl_down(sum, off, 64);
  __shared__ float red[4];
  if ((threadIdx.x & 63) == 0) red[threadIdx.x >> 6] = sum;
  __syncthreads();
  if (threadIdx.x == 0) {
    float tot = red[0] + red[1] + red[2] + red[3];
    inv_norm[row] = rsqrtf(fmaxf(tot, 1e-10f));
  }
}

__global__ __launch_bounds__(256) void sim_kernel(const float* __restrict__ q,
                                                  const float* __restrict__ s,
                                                  const float* __restrict__ inv_norm,
                                                  float* __restrict__ sim) {
  __shared__ float As[16][64];
  __shared__ float Bs[16][64];
  const int t = threadIdx.x;
  const int b = blockIdx.z;
  const int row0 = blockIdx.y * 64;
  const int col0 = blockIdx.x * 64;
  const float* qb = q + (size_t)b * NQ * DIM;
  const float* sb = s + (size_t)b * NS * DIM;
  const int am = t >> 2, ak = (t & 3) * 4;
  const int tm = (t >> 4) * 4, tn = (t & 15) * 4;
  float acc[4][4] = {};
  for (int k0 = 0; k0 < DIM; k0 += 16) {
    float4 av = make_float4(0.f, 0.f, 0.f, 0.f);
    if (row0 + am < NQ)
      av = *(const float4*)(qb + (size_t)(row0 + am) * DIM + k0 + ak);
    As[ak + 0][am] = av.x;
    As[ak + 1][am] = av.y;
    As[ak + 2][am] = av.z;
    As[ak + 3][am] = av.w;
    float4 bv = make_float4(0.f, 0.f, 0.f, 0.f);
    if (col0 + am < NS)
      bv = *(const float4*)(sb + (size_t)(col0 + am) * DIM + k0 + ak);
    Bs[ak + 0][am] = bv.x;
    Bs[ak + 1][am] = bv.y;
    Bs[ak + 2][am] = bv.z;
    Bs[ak + 3][am] = bv.w;
    __syncthreads();
#pragma unroll
    for (int k = 0; k < 16; ++k) {
      float4 a4 = *(const float4*)&As[k][tm];
      float4 b4 = *(const float4*)&Bs[k][tn];
      float av_[4] = {a4.x, a4.y, a4.z, a4.w};
      float bv_[4] = {b4.x, b4.y, b4.z, b4.w};
#pragma unroll
      for (int i = 0; i < 4; ++i)
#pragma unroll
        for (int j = 0; j < 4; ++j) acc[i][j] += av_[i] * bv_[j];
    }
    __syncthreads();
  }
#pragma unroll
  for (int i = 0; i < 4; ++i) {
    int m = row0 + tm + i;
    if (m >= NQ) continue;
#pragma unroll
    for (int j = 0; j < 4; ++j) {
      int n = col0 + tn + j;
      if (n >= NS) continue;
      sim[((size_t)b * NQ + m) * NS + n] = acc[i][j] * inv_norm[b * NS + n];
    }
  }
}

// ---------------------------------------------------------------------------
extern "C" void kernel_launch(void* const* d_in, const int* in_sizes, int n_in,
                              void* d_out, int out_size, void* d_ws,
                              size_t ws_size, hipStream_t stream) {
  const float* support = (const float*)d_in[0];
  const float* query   = (const float*)d_in[1];
  const float* onehot  = (const float*)d_in[2];
  const float* W       = (const float*)d_in[3];
  const float* bias    = (const float*)d_in[4];

  char* wsb = (char*)d_ws;

  // --- Gram-matrix path workspace layout ---
  // Z    : 6400*2048*4      = 52,428,800   @ 0            (dead after norm_v)
  // S1   : 6400*2048*2      = 26,214,400   @ 52,428,800   (dead after Z-gemm)
  // S2   :                  = 26,214,400   @ 78,643,200   (dead after Z-gemm)
  // Wr1  : 2048*2048*2      =  8,388,608   @ 104,857,600  (dead after G-gemm)
  // Wr2  :                  =  8,388,608   @ 113,246,208  (dead after G-gemm)
  // G1   :                  =  8,388,608   @ 121,634,816  (dead after Z-gemm)
  // G2   :                  =  8,388,608   @ 130,023,424  (dead after Z-gemm)
  // Z1   : 6400*2048*2      = 26,214,400   @ 138,412,032
  // Z2   :                  = 26,214,400   @ 164,626,432
  // part : 4*64*320*112*4   = 36,700,160   @ 52,428,800   (overlays dead S1/S2)
  // inv  :  6400*4          =     25,600   @ 190,840,832
  // vv   :  6400*4          =     25,600   @ 190,866,432
  // wb   :  2048*4          =      8,192   @ 190,892,032
  // bb   :  256 (pad)                      @ 190,900,224
  // upart: 4*64*320*4       =    327,680   @ 190,900,480
  const size_t NEED = 191228160;

  if (ws_size >= NEED) {
    float* Z              = (float*)wsb;
    unsigned short* S1    = (unsigned short*)(wsb + (size_t)52428800);
    unsigned short* S2    = (unsigned short*)(wsb + (size_t)78643200);
    unsigned short* Wr1   = (unsigned short*)(wsb + (size_t)104857600);
    unsigned short* Wr2   = (unsigned short*)(wsb + (size_t)113246208);
    unsigned short* G1    = (unsigned short*)(wsb + (size_t)121634816);
    unsigned short* G2    = (unsigned short*)(wsb + (size_t)130023424);
    unsigned short* Z1    = (unsigned short*)(wsb + (size_t)138412032);
    unsigned short* Z2    = (unsigned short*)(wsb + (size_t)164626432);
    float* part           = (float*)(wsb + (size_t)52428800);  // overlays S1/S2
    float* inv_norm       = (float*)(wsb + (size_t)190840832);
    float* vv             = (float*)(wsb + (size_t)190866432);
    float* wb             = (float*)(wsb + (size_t)190892032);
    float* bb             = (float*)(wsb + (size_t)190900224);
    float* upart          = (float*)(wsb + (size_t)190900480);

    // pre-splits: W (A and B of G-gemm) and support (A of Z-gemm)
    esplit2<<<DIM * DIM / 1024, 256, 0, stream>>>(W, Wr1, Wr2, DIM * DIM / 4);
    esplit2<<<MS * DIM / 1024, 256, 0, stream>>>(support, S1, S2,
                                                 MS * DIM / 4);
    // G = W @ W^T, all-bf16: A=Wr1/Wr2, B=Wr1/Wr2 (row-major W = [n][k]).
    // Fused epilogue writes G1/G2 (no fp32 G; G symmetric -> row split = B split)
    gemm_bb3<1, 2><<<dim3(DIM / 128, DIM / 128), 256, 0, stream>>>(
        Wr1, Wr2, Wr1, Wr2, nullptr, G1, G2);
    // Z = Xs @ G, all-bf16: A=S1/S2, B=G1/G2; writes Z fp32 + Z1/Z2 splits.
    gemm_bb3<2, 2><<<dim3(DIM / 256, MS / 128), 256, 0, stream>>>(
        S1, S2, G1, G2, Z, Z1, Z2);
    // bias terms: wb = W@b, bb = ||b||^2, v = Xs@wb (fused in norm_v)
    gemv_wb<<<DIM, 256, 0, stream>>>(W, bias, wb, bb);
    norm_v<<<MS, 256, 0, stream>>>(Z, support, wb, bb, inv_norm, vv);
    // sim partials (k-split x4, MFMA, LDS-free) + fused u = Xq.wb partials
    sim2_part<<<dim3(5, BATCH, KSPL), 256, 0, stream>>>(query, Z1, Z2, wb,
                                                        part, upart);
    // partial-sum + affine + softmax + onehot contract + argmax
    softmax_part<<<MQ / 4, 256, 0, stream>>>(part, upart, vv, bb, inv_norm,
                                             onehot, (float*)d_out);
  } else {
    // proven R1 fallback (fits in 217.5 MB)
    float* s = (float*)wsb;
    float* q = (float*)(wsb + (size_t)52428800);
    float* inv_norm = q + (size_t)MQ * DIM;
    float* sim      = inv_norm + MS;
    gemm_xw<<<dim3(MS / 64, DIM / 64), 256, 0, stream>>>(support, W, bias, s);
    gemm_xw<<<dim3(MQ / 64, DIM / 64), 256, 0, stream>>>(query, W, bias, q);
    norm_kernel<<<MS, 256, 0, stream>>>(s, inv_norm);
    sim_kernel<<<dim3(2, 5, BATCH), 256, 0, stream>>>(q, s, inv_norm, sim);
    softmax_fb<<<MQ / 4, 256, 0, stream>>>(sim, onehot, (float*)d_out);
  }
}